// Round 18
// baseline (335.533 us; speedup 1.0000x reference)
//
#include <hip/hip_runtime.h>
#include <hip/hip_bf16.h>
#include <math.h>

#define TOKENS 8192
#define IN_F   1024
#define HID_F  4096
#define OUT_F  1024
#define NEXP   8
#define TSLOTS 40   // max total 256-row M-tiles: TOKENS/256 + NEXP partials

typedef __attribute__((ext_vector_type(8))) short bf16x8;
typedef __attribute__((ext_vector_type(4))) float f32x4;
typedef __attribute__((ext_vector_type(8))) unsigned short u16x8;

__device__ __forceinline__ unsigned short f2bf(float f) {
    unsigned int u = __float_as_uint(f);
    u += 0x7fffu + ((u >> 16) & 1u);   // round-to-nearest-even
    return (unsigned short)(u >> 16);
}

__device__ __forceinline__ float bf2f(unsigned short s) {
    return __uint_as_float((unsigned)s << 16);
}

__device__ __forceinline__ void gload_lds16(const unsigned short* g, unsigned char* lds) {
    __builtin_amdgcn_global_load_lds(
        (const __attribute__((address_space(1))) void*)g,
        (__attribute__((address_space(3))) void*)lds, 16, 0, 0);
}

// ---------------- sort + tile-table build (1024 thr, R13-verified) ----------
__global__ void sort_kernel(const int* __restrict__ idx, int* __restrict__ perm,
                            int* __restrict__ off, int* __restrict__ table) {
    __shared__ int cnt[NEXP];
    __shared__ int base[NEXP];
    const int tid = threadIdx.x, lane = tid & 63;
    if (tid < NEXP) cnt[tid] = 0;
    __syncthreads();
    for (int i = tid; i < TOKENS; i += 1024) {
        int e = idx[i];
#pragma unroll
        for (int ex = 0; ex < NEXP; ++ex) {
            unsigned long long m = __ballot(e == ex);
            if (lane == 0 && m) atomicAdd(&cnt[ex], __popcll(m));
        }
    }
    __syncthreads();
    if (tid == 0) {
        int s = 0;
        for (int e = 0; e < NEXP; ++e) { off[e] = s; base[e] = s; s += cnt[e]; }
        off[NEXP] = s;
        int t = 0;
        for (int e = 0; e < NEXP; ++e)
            for (int m0 = off[e]; m0 < off[e + 1]; m0 += 256)
                table[t++] = (e << 13) | m0;
        for (; t < TSLOTS; ++t) table[t] = -1;
    }
    __syncthreads();
    for (int i = tid; i < TOKENS; i += 1024) {
        int e = idx[i];
#pragma unroll
        for (int ex = 0; ex < NEXP; ++ex) {
            unsigned long long m = __ballot(e == ex);
            if (e == ex) {
                int lead = (int)__ffsll((long long)m) - 1;
                int pos = 0;
                if (lane == lead) pos = atomicAdd(&base[ex], __popcll(m));
                pos = __shfl(pos, lead);
                pos += __popcll(m & ((1ULL << lane) - 1ULL));
                perm[pos] = i;
            }
        }
    }
}

// ------- transpose tile body: fp32 [R][C] block (by,bx) -> bf16 [C][R] ------
__device__ __forceinline__ void transp_tile(const float* __restrict__ in,
                                            unsigned short* __restrict__ out,
                                            int R, int C, int e, int by, int bx,
                                            unsigned short* T, int st) {
    const int r0 = by * 64, c0 = bx * 64;
    const int rr = st >> 4, cc = st & 15;
    const float* ip = in + ((size_t)e * R + r0) * C + c0;
#pragma unroll
    for (int p = 0; p < 4; ++p) {
        int r = p * 16 + rr;
        float4 v = *(const float4*)(ip + (size_t)r * C + cc * 4);
        T[(cc * 4 + 0) * 65 + r] = f2bf(v.x);
        T[(cc * 4 + 1) * 65 + r] = f2bf(v.y);
        T[(cc * 4 + 2) * 65 + r] = f2bf(v.z);
        T[(cc * 4 + 3) * 65 + r] = f2bf(v.w);
    }
    __syncthreads();
    unsigned short* op = out + ((size_t)e * C + c0) * R + r0;
    const int c = st >> 2, ch = st & 3;
    u16x8 a, b;
#pragma unroll
    for (int i = 0; i < 8; ++i) a[i] = T[c * 65 + ch * 16 + i];
#pragma unroll
    for (int i = 0; i < 8; ++i) b[i] = T[c * 65 + ch * 16 + 8 + i];
    *(u16x8*)(op + (size_t)c * R + ch * 16) = a;
    *(u16x8*)(op + (size_t)c * R + ch * 16 + 8) = b;
}

// ---------------- standalone transpose (fallback path) ----------------------
__global__ void transp(const float* __restrict__ in, unsigned short* __restrict__ out,
                       int R, int C) {
    __shared__ unsigned short T[64 * 65];
    transp_tile(in, out, R, C, blockIdx.z, blockIdx.y, blockIdx.x, T, threadIdx.x);
}

// ------- fused pre-pass: gather-x (blocks 0..8191) + W1 transpose (R16) -----
__global__ void fused_pre(const float* __restrict__ x, const int* __restrict__ perm,
                          unsigned short* __restrict__ xg,
                          const float* __restrict__ w1, unsigned short* __restrict__ w1t) {
    __shared__ unsigned short T[64 * 65];
    const int bid = blockIdx.x, t = threadIdx.x;
    if (bid < TOKENS) {
        const int src = perm[bid];
        float4 v = *(const float4*)(x + (size_t)src * IN_F + t * 4);
        unsigned long long pk =
            (unsigned long long)f2bf(v.x) |
            ((unsigned long long)f2bf(v.y) << 16) |
            ((unsigned long long)f2bf(v.z) << 32) |
            ((unsigned long long)f2bf(v.w) << 48);
        *(unsigned long long*)(xg + (size_t)bid * IN_F + t * 4) = pk;
        return;
    }
    const int id = bid - TOKENS;
    const int e = id >> 10, rem = id & 1023;
    const int by = rem >> 6, bx = rem & 63;
    transp_tile(w1, w1t, IN_F, HID_F, e, by, bx, T, t);
}

// ------- reduce: out[perm[row]] += P1[row] + P2[row] + P3[row] (bf16) -------
__global__ void reduce3(const unsigned short* __restrict__ P,
                        const int* __restrict__ perm, float* __restrict__ out) {
    const int t = threadIdx.x;
#pragma unroll 1
    for (int r = 0; r < 8; ++r) {
        const int row = blockIdx.x * 8 + r;
        const int tok = perm[row];
        const size_t o1 = (size_t)row * OUT_F + t * 4;
        ushort4 a = *(const ushort4*)(P + o1);
        ushort4 b = *(const ushort4*)(P + 8388608 + o1);
        ushort4 c = *(const ushort4*)(P + 16777216 + o1);
        float* op = out + (size_t)tok * OUT_F + t * 4;
        float4 o = *(float4*)op;
        o.x += bf2f(a.x) + bf2f(b.x) + bf2f(c.x);
        o.y += bf2f(a.y) + bf2f(b.y) + bf2f(c.y);
        o.z += bf2f(a.z) + bf2f(b.z) + bf2f(c.z);
        o.w += bf2f(a.w) + bf2f(b.w) + bf2f(c.w);
        *(float4*)op = o;
    }
}

// -------- grouped GEMM: 256x256, BK=64, 8 waves, DEEP-STAGGER 8-phase -------
// R16-verified schedule (passed). NSPLIT-way K split (R9-verified epilogue):
// split ks covers k in [ks*NT_*64, (ks+1)*NT_*64). ks=0 writes out=bias+
// partial (fp32, scattered by perm); ks>0 writes bf16 partial (coalesced).
#define RD_A(RB, HALF) \
  _Pragma("unroll") for (int m_ = 0; m_ < 4; ++m_) { \
    const int row_ = wr * 128 + (HALF) * 64 + m_ * 16 + lr; \
    _Pragma("unroll") for (int kk_ = 0; kk_ < 2; ++kk_) \
      aR[m_][kk_] = *(const bf16x8*)((RB) + row_ * 128 + (((kk_ * 4 + hk) << 4) ^ xorc)); }

#define RD_B(RB, NH, DST) \
  _Pragma("unroll") for (int nn_ = 0; nn_ < 2; ++nn_) { \
    const int row_ = wc * 64 + ((NH) * 2 + nn_) * 16 + lr; \
    _Pragma("unroll") for (int kk_ = 0; kk_ < 2; ++kk_) \
      DST[nn_][kk_] = *(const bf16x8*)((RB) + 32768 + row_ * 128 + (((kk_ * 4 + hk) << 4) ^ xorc)); }

#define MFMA_Q(MH, NH, B) \
  __builtin_amdgcn_s_setprio(1); \
  _Pragma("unroll") for (int m_ = 0; m_ < 4; ++m_) \
    _Pragma("unroll") for (int nn_ = 0; nn_ < 2; ++nn_) \
      _Pragma("unroll") for (int kk_ = 0; kk_ < 2; ++kk_) \
        acc[(MH) * 4 + m_][(NH) * 2 + nn_] = __builtin_amdgcn_mfma_f32_16x16x32_bf16( \
            aR[m_][kk_], B[nn_][kk_], acc[(MH) * 4 + m_][(NH) * 2 + nn_], 0, 0, 0); \
  __builtin_amdgcn_s_setprio(0);

template<int KROW, int NT_, int ND, int NSPLIT, bool GELU>
__launch_bounds__(512, 2)
__global__ void moe_gemm8p(const unsigned short* __restrict__ A,
                           const unsigned short* __restrict__ W,
                           const float* __restrict__ bias,
                           const int* __restrict__ perm,
                           const int* __restrict__ off,
                           const int* __restrict__ table,
                           void* __restrict__ outp,
                           const float* __restrict__ w2src,
                           unsigned short* __restrict__ w2t,
                           unsigned short* __restrict__ Ppart) {
    const int nwg = (ND / 256) * TSLOTS * NSPLIT;

    __shared__ __align__(16) unsigned char L[131072];  // 2 buf x (A 32K + B 32K)
    const int tid = threadIdx.x;

    if ((int)blockIdx.x >= nwg) {
        // ---- fused W2 transpose: [E][4096][1024] -> [E][1024][4096] ----
        const int sub = tid >> 8, st = tid & 255;
        const int id2 = ((int)blockIdx.x - nwg) * 2 + sub;
        const int e = id2 >> 10, rem = id2 & 1023;
        const int by = rem >> 4, bx = rem & 15;
        unsigned short* T = (unsigned short*)(L + sub * 8448);
        transp_tile(w2src, w2t, HID_F, OUT_F, e, by, bx, T, st);
        return;
    }

    const int chunk = nwg >> 3;
    const int logical = ((int)blockIdx.x & 7) * chunk + ((int)blockIdx.x >> 3);
    const int nper = (ND / 256) * TSLOTS;
    const int ks  = logical / nper;
    const int rem0 = logical - ks * nper;
    // panel-paired decode: consecutive logicals = same slot, adjacent panels
    const int pr   = rem0 / (2 * TSLOTS);
    const int rem2 = rem0 - pr * (2 * TSLOTS);
    const int ts = rem2 >> 1;
    const int nt = pr * 2 + (rem2 & 1);
    const int te = table[ts];
    if (te < 0) return;
    const int e  = te >> 13;
    const int m0 = te & 8191;
    const int sege = off[e + 1];
    const int n0 = nt * 256;
    const int k_off = ks * (NT_ * 64);

    const int wid = tid >> 6, lane = tid & 63;
    const int wr = wid >> 2, wc = wid & 3;
    const int lr = lane & 15, hk = lane >> 4;

    const unsigned short* We = W + (size_t)e * ND * KROW + (size_t)n0 * KROW;

    const int srow8 = lane >> 3;
    const int sch   = (lane & 7) ^ srow8;   // pre-swizzled source chunk
    const unsigned short* aSrc[4];
    const unsigned short* wSrc[4];
#pragma unroll
    for (int cc = 0; cc < 4; ++cc) {
        int rt = cc * 64 + wid * 8 + srow8;
        int ga = m0 + rt; if (ga > TOKENS - 1) ga = TOKENS - 1;
        aSrc[cc] = A  + (size_t)ga * KROW + k_off + sch * 8;
        wSrc[cc] = We + (size_t)rt * KROW + k_off + sch * 8;
    }
    const int dstBase = wid * 1024;

    // h: 0=A rows0-127, 1=A rows128-255, 2=B rows0-127, 3=B rows128-255
    auto stageH = [&](int tile, int h) {
        const int buf = (tile & 1) * 65536;
        const int op  = (h >> 1) * 32768;
        const int c0_ = (h & 1) * 2;
        const int ko  = tile * 64;
#pragma unroll
        for (int j = 0; j < 2; ++j) {
            int cc = c0_ + j;
            const unsigned short* s = (h < 2) ? (aSrc[cc] + ko) : (wSrc[cc] + ko);
            gload_lds16(s, L + buf + op + cc * 8192 + dstBase);
        }
    };

    f32x4 acc[8][4];
#pragma unroll
    for (int i = 0; i < 8; ++i)
#pragma unroll
        for (int j = 0; j < 4; ++j) acc[i][j] = (f32x4){0.f, 0.f, 0.f, 0.f};

    bf16x8 aR[4][2], b0R[2][2], b1R[2][2];
    const int xorc = (lr & 7) << 4;
    const unsigned char* rb0 = L;
    const unsigned char* rb1 = L + 65536;

    // prologue: T0 all 4 halves + B0,B1(T1); wait T0 landed; rendezvous.
    stageH(0, 0); stageH(0, 1); stageH(0, 2); stageH(0, 3);
    stageH(1, 2); stageH(1, 3);
    asm volatile("s_waitcnt vmcnt(4)" ::: "memory");
    __builtin_amdgcn_s_barrier();
    __builtin_amdgcn_sched_barrier(0);

#pragma unroll 1
    for (int i = 0; i < NT_ / 2; ++i) {
        const int T1 = 2 * i + 1;
        const bool lastIt = (i == NT_ / 2 - 1);
        // ---- ph0: q00 of T0 ----
        RD_A(rb0, 0); RD_B(rb0, 0, b0R);
        stageH(T1, 0);                       // A0(T1)
        __builtin_amdgcn_s_barrier();
        MFMA_Q(0, 0, b0R);
        __builtin_amdgcn_s_barrier();
        // ---- ph1: q01 ----
        RD_B(rb0, 1, b1R);
        stageH(T1, 1);                       // A1(T1)
        __builtin_amdgcn_s_barrier();
        MFMA_Q(0, 1, b1R);
        __builtin_amdgcn_s_barrier();
        // ---- ph2: q11 ----
        RD_A(rb0, 1);
        if (!lastIt) stageH(T1 + 1, 2);      // B0(T0+2)
        __builtin_amdgcn_s_barrier();
        MFMA_Q(1, 1, b1R);
        __builtin_amdgcn_s_barrier();
        // ---- ph3: q10 (b0R persists from ph0); publish T1 ----
        if (!lastIt) stageH(T1 + 1, 3);      // B1(T0+2)
        __builtin_amdgcn_s_barrier();
        MFMA_Q(1, 0, b0R);
        if (lastIt) { asm volatile("s_waitcnt vmcnt(0)" ::: "memory"); }
        else        { asm volatile("s_waitcnt vmcnt(4)" ::: "memory"); }
        __builtin_amdgcn_s_barrier();        // T1 visible to all waves
        __builtin_amdgcn_sched_barrier(0);
        // ---- ph4: q00 of T1 ----
        RD_A(rb1, 0); RD_B(rb1, 0, b0R);
        if (!lastIt) stageH(T1 + 1, 0);      // A0(T0+2)
        __builtin_amdgcn_s_barrier();
        MFMA_Q(0, 0, b0R);
        __builtin_amdgcn_s_barrier();
        // ---- ph5: q01 ----
        RD_B(rb1, 1, b1R);
        if (!lastIt) stageH(T1 + 1, 1);      // A1(T0+2)
        __builtin_amdgcn_s_barrier();
        MFMA_Q(0, 1, b1R);
        __builtin_amdgcn_s_barrier();
        // ---- ph6: q11 ----
        RD_A(rb1, 1);
        if (!lastIt) stageH(T1 + 2, 2);      // B0(T1+2)
        __builtin_amdgcn_s_barrier();
        MFMA_Q(1, 1, b1R);
        __builtin_amdgcn_s_barrier();
        // ---- ph7: q10 (b0R from ph4); publish T0+2 ----
        if (!lastIt) stageH(T1 + 2, 3);      // B1(T1+2)
        __builtin_amdgcn_s_barrier();
        MFMA_Q(1, 0, b0R);
        if (!lastIt) { asm volatile("s_waitcnt vmcnt(4)" ::: "memory"); }
        __builtin_amdgcn_s_barrier();        // T0+2 visible to all waves
        __builtin_amdgcn_sched_barrier(0);
    }

    // epilogue
    const float* be = bias + (size_t)e * ND + n0;
#pragma unroll
    for (int m = 0; m < 8; ++m) {
#pragma unroll
        for (int r = 0; r < 4; ++r) {
            int row = wr * 128 + m * 16 + hk * 4 + r;
            int grow = m0 + row;
            if (grow >= sege) continue;
            if constexpr (GELU) {
                unsigned short* h = (unsigned short*)outp;
                size_t base = (size_t)grow * ND + n0;
#pragma unroll
                for (int n = 0; n < 4; ++n) {
                    int col = wc * 64 + n * 16 + lr;
                    float v = acc[m][n][r] + be[col];
                    float u = v * (0.7978845608f + 0.0356774081f * v * v);
                    float g = v / (1.0f + __expf(-2.0f * u));
                    h[base + col] = f2bf(g);
                }
            } else {
                if (NSPLIT == 1 || ks == 0) {
                    float* out = (float*)outp;
                    int tok = perm[grow];
                    size_t base = (size_t)tok * ND + n0;
#pragma unroll
                    for (int n = 0; n < 4; ++n) {
                        int col = wc * 64 + n * 16 + lr;
                        out[base + col] = acc[m][n][r] + be[col];
                    }
                } else {
                    unsigned short* P = Ppart + (size_t)(ks - 1) * TOKENS * ND;
                    size_t base = (size_t)grow * ND + n0;
#pragma unroll
                    for (int n = 0; n < 4; ++n) {
                        int col = wc * 64 + n * 16 + lr;
                        P[base + col] = f2bf(acc[m][n][r]);
                    }
                }
            }
        }
    }
}

extern "C" void kernel_launch(void* const* d_in, const int* in_sizes, int n_in,
                              void* d_out, int out_size, void* d_ws, size_t ws_size,
                              hipStream_t stream) {
    const float* x   = (const float*)d_in[0];
    const int*   idx = (const int*)d_in[1];
    const float* w1  = (const float*)d_in[2];
    const float* w2  = (const float*)d_in[3];
    const float* b1  = (const float*)d_in[4];
    const float* b2  = (const float*)d_in[5];
    float* out = (float*)d_out;

    int* perm  = (int*)d_ws;
    int* off   = perm + TOKENS;
    int* table = off + 16;
    unsigned short* xg  = (unsigned short*)((char*)d_ws + 65536);
    unsigned short* h   = xg + (size_t)TOKENS * IN_F;             // 64 MB
    unsigned short* w1t = h + (size_t)TOKENS * HID_F;             // 64 MB
    unsigned short* w2t = w1t + (size_t)NEXP * IN_F * HID_F;      // 64 MB (fused only)
    unsigned short* P   = w1t;   // w1t dead after GEMM1 -> 48 MB partials
    const size_t need_fused = 65536
        + (size_t)TOKENS * IN_F * 2
        + (size_t)TOKENS * HID_F * 2
        + (size_t)NEXP * IN_F * HID_F * 2 * 2;
    const bool fused = (ws_size >= need_fused);

    hipLaunchKernelGGL(sort_kernel, dim3(1), dim3(1024), 0, stream, idx, perm, off, table);
    hipLaunchKernelGGL(fused_pre, dim3(TOKENS + NEXP * (IN_F / 64) * (HID_F / 64)),
                       dim3(256), 0, stream, x, perm, xg, w1, w1t);

    const int g1 = (HID_F / 256) * TSLOTS;                    // 640 GEMM1 tiles
    const int t2 = NEXP * (OUT_F / 64) * (HID_F / 64) / 2;    // 4096 W2t blocks
    if (fused) {
        hipLaunchKernelGGL((moe_gemm8p<IN_F, 16, HID_F, 1, true>), dim3(g1 + t2), dim3(512),
                           0, stream, xg, w1t, b1, perm, off, table, (void*)h, w2, w2t,
                           (unsigned short*)nullptr);
        // GEMM2: 4-way K split -> 640 quarter-length blocks (2.5 rounds)
        hipLaunchKernelGGL((moe_gemm8p<HID_F, 16, OUT_F, 4, false>),
                           dim3((OUT_F / 256) * TSLOTS * 4), dim3(512),
                           0, stream, h, w2t, b2, perm, off, table, (void*)out,
                           (const float*)nullptr, (unsigned short*)nullptr, P);
        hipLaunchKernelGGL(reduce3, dim3(TOKENS / 8), dim3(256), 0, stream, P, perm, out);
    } else {
        hipLaunchKernelGGL((moe_gemm8p<IN_F, 16, HID_F, 1, true>), dim3(g1), dim3(512),
                           0, stream, xg, w1t, b1, perm, off, table, (void*)h,
                           (const float*)nullptr, (unsigned short*)nullptr,
                           (unsigned short*)nullptr);
        hipLaunchKernelGGL(transp, dim3(OUT_F / 64, HID_F / 64, NEXP), dim3(256), 0, stream,
                           w2, w1t, HID_F, OUT_F);
        hipLaunchKernelGGL((moe_gemm8p<HID_F, 64, OUT_F, 1, false>),
                           dim3((OUT_F / 256) * TSLOTS), dim3(512),
                           0, stream, h, w1t, b2, perm, off, table, (void*)out,
                           (const float*)nullptr, (unsigned short*)nullptr,
                           (unsigned short*)nullptr);
    }
}

// Round 19
// 313.846 us; speedup vs baseline: 1.0691x; 1.0691x over previous
//
#include <hip/hip_runtime.h>
#include <hip/hip_bf16.h>
#include <math.h>

#define TOKENS 8192
#define IN_F   1024
#define HID_F  4096
#define OUT_F  1024
#define NEXP   8
#define TSLOTS 40   // max total 256-row M-tiles: TOKENS/256 + NEXP partials

typedef __attribute__((ext_vector_type(8))) short bf16x8;
typedef __attribute__((ext_vector_type(4))) float f32x4;
typedef __attribute__((ext_vector_type(8))) unsigned short u16x8;

__device__ __forceinline__ unsigned short f2bf(float f) {
    unsigned int u = __float_as_uint(f);
    u += 0x7fffu + ((u >> 16) & 1u);   // round-to-nearest-even
    return (unsigned short)(u >> 16);
}

__device__ __forceinline__ void gload_lds16(const unsigned short* g, unsigned char* lds) {
    __builtin_amdgcn_global_load_lds(
        (const __attribute__((address_space(1))) void*)g,
        (__attribute__((address_space(3))) void*)lds, 16, 0, 0);
}

// ---------------- sort + tile-table build (256-row tiles) -------------------
__global__ void sort_kernel(const int* __restrict__ idx, int* __restrict__ perm,
                            int* __restrict__ off, int* __restrict__ table) {
    __shared__ int cnt[NEXP];
    __shared__ int base[NEXP];
    const int tid = threadIdx.x, lane = tid & 63;
    if (tid < NEXP) cnt[tid] = 0;
    __syncthreads();
    for (int i = tid; i < TOKENS; i += 1024) {
        int e = idx[i];
#pragma unroll
        for (int ex = 0; ex < NEXP; ++ex) {
            unsigned long long m = __ballot(e == ex);
            if (lane == 0 && m) atomicAdd(&cnt[ex], __popcll(m));
        }
    }
    __syncthreads();
    if (tid == 0) {
        int s = 0;
        for (int e = 0; e < NEXP; ++e) { off[e] = s; base[e] = s; s += cnt[e]; }
        off[NEXP] = s;
        int t = 0;
        for (int e = 0; e < NEXP; ++e)
            for (int m0 = off[e]; m0 < off[e + 1]; m0 += 256)
                table[t++] = (e << 13) | m0;
        for (; t < TSLOTS; ++t) table[t] = -1;
    }
    __syncthreads();
    for (int i = tid; i < TOKENS; i += 1024) {
        int e = idx[i];
#pragma unroll
        for (int ex = 0; ex < NEXP; ++ex) {
            unsigned long long m = __ballot(e == ex);
            if (e == ex) {
                int lead = (int)__ffsll((long long)m) - 1;
                int pos = 0;
                if (lane == lead) pos = atomicAdd(&base[ex], __popcll(m));
                pos = __shfl(pos, lead);
                pos += __popcll(m & ((1ULL << lane) - 1ULL));
                perm[pos] = i;
            }
        }
    }
}

// ------- transpose tile body: fp32 [R][C] block (by,bx) -> bf16 [C][R] ------
__device__ __forceinline__ void transp_tile(const float* __restrict__ in,
                                            unsigned short* __restrict__ out,
                                            int R, int C, int e, int by, int bx,
                                            unsigned short* T, int st) {
    const int r0 = by * 64, c0 = bx * 64;
    const int rr = st >> 4, cc = st & 15;
    const float* ip = in + ((size_t)e * R + r0) * C + c0;
#pragma unroll
    for (int p = 0; p < 4; ++p) {
        int r = p * 16 + rr;
        float4 v = *(const float4*)(ip + (size_t)r * C + cc * 4);
        T[(cc * 4 + 0) * 65 + r] = f2bf(v.x);
        T[(cc * 4 + 1) * 65 + r] = f2bf(v.y);
        T[(cc * 4 + 2) * 65 + r] = f2bf(v.z);
        T[(cc * 4 + 3) * 65 + r] = f2bf(v.w);
    }
    __syncthreads();
    unsigned short* op = out + ((size_t)e * C + c0) * R + r0;
    const int c = st >> 2, ch = st & 3;
    u16x8 a, b;
#pragma unroll
    for (int i = 0; i < 8; ++i) a[i] = T[c * 65 + ch * 16 + i];
#pragma unroll
    for (int i = 0; i < 8; ++i) b[i] = T[c * 65 + ch * 16 + 8 + i];
    *(u16x8*)(op + (size_t)c * R + ch * 16) = a;
    *(u16x8*)(op + (size_t)c * R + ch * 16 + 8) = b;
}

// ---------------- standalone transpose (fallback path) ----------------------
__global__ void transp(const float* __restrict__ in, unsigned short* __restrict__ out,
                       int R, int C) {
    __shared__ unsigned short T[64 * 65];
    transp_tile(in, out, R, C, blockIdx.z, blockIdx.y, blockIdx.x, T, threadIdx.x);
}

// ------- fused pre-pass: gather-x (blocks 0..8191) + W1 transpose -----------
__global__ void fused_pre(const float* __restrict__ x, const int* __restrict__ perm,
                          unsigned short* __restrict__ xg,
                          const float* __restrict__ w1, unsigned short* __restrict__ w1t) {
    __shared__ unsigned short T[64 * 65];
    const int bid = blockIdx.x, t = threadIdx.x;
    if (bid < TOKENS) {
        const int src = perm[bid];
        float4 v = *(const float4*)(x + (size_t)src * IN_F + t * 4);
        unsigned long long pk =
            (unsigned long long)f2bf(v.x) |
            ((unsigned long long)f2bf(v.y) << 16) |
            ((unsigned long long)f2bf(v.z) << 32) |
            ((unsigned long long)f2bf(v.w) << 48);
        *(unsigned long long*)(xg + (size_t)bid * IN_F + t * 4) = pk;
        return;
    }
    const int id = bid - TOKENS;
    const int e = id >> 10, rem = id & 1023;
    const int by = rem >> 6, bx = rem & 63;
    transp_tile(w1, w1t, IN_F, HID_F, e, by, bx, T, t);
}

// -------- grouped GEMM: 256x256, BK=64, 8 waves, 8-phase counted-vmcnt ------
// R8/R13-verified schedule. Logical order = PANEL-PAIRED: consecutive
// logicals share the m-slot across two adjacent n-panels -> the A-tile just
// fetched by block k is reused by block k+1 on the same XCD (A L2 reuse);
// W working set = 2 panels (still L2-fit). Bijective remap only.
#define RD_A(RB, HALF) \
  _Pragma("unroll") for (int m_ = 0; m_ < 4; ++m_) { \
    const int row_ = wr * 128 + (HALF) * 64 + m_ * 16 + lr; \
    _Pragma("unroll") for (int kk_ = 0; kk_ < 2; ++kk_) \
      aR[m_][kk_] = *(const bf16x8*)((RB) + row_ * 128 + (((kk_ * 4 + hk) << 4) ^ xorc)); }

#define RD_B(RB, NH, DST) \
  _Pragma("unroll") for (int nn_ = 0; nn_ < 2; ++nn_) { \
    const int row_ = wc * 64 + ((NH) * 2 + nn_) * 16 + lr; \
    _Pragma("unroll") for (int kk_ = 0; kk_ < 2; ++kk_) \
      DST[nn_][kk_] = *(const bf16x8*)((RB) + 32768 + row_ * 128 + (((kk_ * 4 + hk) << 4) ^ xorc)); }

#define MFMA_Q(MH, NH, B) \
  __builtin_amdgcn_s_setprio(1); \
  _Pragma("unroll") for (int m_ = 0; m_ < 4; ++m_) \
    _Pragma("unroll") for (int nn_ = 0; nn_ < 2; ++nn_) \
      _Pragma("unroll") for (int kk_ = 0; kk_ < 2; ++kk_) \
        acc[(MH) * 4 + m_][(NH) * 2 + nn_] = __builtin_amdgcn_mfma_f32_16x16x32_bf16( \
            aR[m_][kk_], B[nn_][kk_], acc[(MH) * 4 + m_][(NH) * 2 + nn_], 0, 0, 0); \
  __builtin_amdgcn_s_setprio(0);

template<int K, int ND, bool GELU>
__launch_bounds__(512, 2)
__global__ void moe_gemm8p(const unsigned short* __restrict__ A,
                           const unsigned short* __restrict__ W,
                           const float* __restrict__ bias,
                           const int* __restrict__ perm,
                           const int* __restrict__ off,
                           const int* __restrict__ table,
                           void* __restrict__ outp,
                           const float* __restrict__ w2src,
                           unsigned short* __restrict__ w2t) {
    const int nwg = (ND / 256) * TSLOTS;

    __shared__ __align__(16) unsigned char L[131072];  // 2 buf x (A 32K + B 32K)
    const int tid = threadIdx.x;

    if ((int)blockIdx.x >= nwg) {
        // ---- fused W2 transpose: [E][4096][1024] -> [E][1024][4096] ----
        const int sub = tid >> 8, st = tid & 255;
        const int id2 = ((int)blockIdx.x - nwg) * 2 + sub;
        const int e = id2 >> 10, rem = id2 & 1023;
        const int by = rem >> 4, bx = rem & 15;
        unsigned short* T = (unsigned short*)(L + sub * 8448);
        transp_tile(w2src, w2t, HID_F, OUT_F, e, by, bx, T, st);
        return;
    }

    const int chunk = nwg >> 3;
    const int logical = ((int)blockIdx.x & 7) * chunk + ((int)blockIdx.x >> 3);
    // panel-paired decode: consecutive logicals = same slot, adjacent panels
    const int pr   = logical / (2 * TSLOTS);
    const int rem2 = logical - pr * (2 * TSLOTS);
    const int ts = rem2 >> 1;
    const int nt = pr * 2 + (rem2 & 1);
    const int te = table[ts];
    if (te < 0) return;
    const int e  = te >> 13;
    const int m0 = te & 8191;
    const int sege = off[e + 1];
    const int n0 = nt * 256;

    const int wid = tid >> 6, lane = tid & 63;
    const int wr = wid >> 2, wc = wid & 3;
    const int lr = lane & 15, hk = lane >> 4;

    const unsigned short* We = W + (size_t)e * ND * K + (size_t)n0 * K;

    const int srow8 = lane >> 3;
    const int sch   = (lane & 7) ^ srow8;   // pre-swizzled source chunk
    const unsigned short* aSrc[4];
    const unsigned short* wSrc[4];
#pragma unroll
    for (int cc = 0; cc < 4; ++cc) {
        int rt = cc * 64 + wid * 8 + srow8;
        int ga = m0 + rt; if (ga > TOKENS - 1) ga = TOKENS - 1;
        aSrc[cc] = A  + (size_t)ga * K + sch * 8;
        wSrc[cc] = We + (size_t)rt * K + sch * 8;
    }
    const int dstBase = wid * 1024;

    constexpr int NT = K / 64;

    auto stageH = [&](int tile, int h) {
        const int buf = (tile & 1) * 65536;
        const int op  = (h >> 1) * 32768;
        const int c0_ = (h & 1) * 2;
        const int ko  = tile * 64;
#pragma unroll
        for (int j = 0; j < 2; ++j) {
            int cc = c0_ + j;
            const unsigned short* s = (h < 2) ? (aSrc[cc] + ko) : (wSrc[cc] + ko);
            gload_lds16(s, L + buf + op + cc * 8192 + dstBase);
        }
    };

    f32x4 acc[8][4];
#pragma unroll
    for (int i = 0; i < 8; ++i)
#pragma unroll
        for (int j = 0; j < 4; ++j) acc[i][j] = (f32x4){0.f, 0.f, 0.f, 0.f};

    bf16x8 aR[4][2], b0R[2][2], b1R[2][2];
    const int xorc = (lr & 7) << 4;
    const unsigned char* rb0 = L;
    const unsigned char* rb1 = L + 65536;

    // prologue: tile0 all 4 halves + A0(tile1); wait own tile0, rendezvous.
    stageH(0, 0); stageH(0, 1); stageH(0, 2); stageH(0, 3);
    stageH(1, 0);
    asm volatile("s_waitcnt vmcnt(2)" ::: "memory");
    __builtin_amdgcn_s_barrier();
    __builtin_amdgcn_sched_barrier(0);

#pragma unroll 1
    for (int i = 0; i < NT / 2; ++i) {
        const int T1 = 2 * i + 1;
        const bool lastIt = (i == NT / 2 - 1);
        // ---- ph0: q00 of T0 ----
        RD_A(rb0, 0); RD_B(rb0, 0, b0R);
        stageH(T1, 1);                       // A1(T1)
        __builtin_amdgcn_s_barrier();
        MFMA_Q(0, 0, b0R);
        __builtin_amdgcn_s_barrier();
        // ---- ph1: q01 ----
        RD_B(rb0, 1, b1R);
        stageH(T1, 2);                       // B0(T1)
        __builtin_amdgcn_s_barrier();
        MFMA_Q(0, 1, b1R);
        __builtin_amdgcn_s_barrier();
        // ---- ph2: q11 ----
        RD_A(rb0, 1);
        stageH(T1, 3);                       // B1(T1)
        __builtin_amdgcn_s_barrier();
        MFMA_Q(1, 1, b1R);
        __builtin_amdgcn_s_barrier();
        // ---- ph3: q10 (b0R persists from ph0); publish T1 ----
        if (!lastIt) stageH(T1 + 1, 0);      // A0(T0+2)
        __builtin_amdgcn_s_barrier();
        MFMA_Q(1, 0, b0R);
        if (lastIt) { asm volatile("s_waitcnt vmcnt(0)" ::: "memory"); }
        else        { asm volatile("s_waitcnt vmcnt(2)" ::: "memory"); }
        __builtin_amdgcn_s_barrier();        // T1 visible to all waves
        __builtin_amdgcn_sched_barrier(0);
        // ---- ph4: q00 of T1 ----
        RD_A(rb1, 0); RD_B(rb1, 0, b0R);
        if (!lastIt) stageH(T1 + 1, 1);      // A1(T0+2)
        __builtin_amdgcn_s_barrier();
        MFMA_Q(0, 0, b0R);
        __builtin_amdgcn_s_barrier();
        // ---- ph5: q01 ----
        RD_B(rb1, 1, b1R);
        if (!lastIt) stageH(T1 + 1, 2);      // B0(T0+2)
        __builtin_amdgcn_s_barrier();
        MFMA_Q(0, 1, b1R);
        __builtin_amdgcn_s_barrier();
        // ---- ph6: q11 ----
        RD_A(rb1, 1);
        if (!lastIt) stageH(T1 + 1, 3);      // B1(T0+2)
        __builtin_amdgcn_s_barrier();
        MFMA_Q(1, 1, b1R);
        __builtin_amdgcn_s_barrier();
        // ---- ph7: q10 (b0R from ph4); publish T0+2 ----
        if (!lastIt) stageH(T1 + 2, 0);      // A0(T1+2)
        __builtin_amdgcn_s_barrier();
        MFMA_Q(1, 0, b0R);
        if (!lastIt) { asm volatile("s_waitcnt vmcnt(2)" ::: "memory"); }
        __builtin_amdgcn_s_barrier();        // T0+2 visible to all waves
        __builtin_amdgcn_sched_barrier(0);
    }

    // epilogue
    const float* be = bias + (size_t)e * ND + n0;
#pragma unroll
    for (int m = 0; m < 8; ++m) {
#pragma unroll
        for (int r = 0; r < 4; ++r) {
            int row = wr * 128 + m * 16 + hk * 4 + r;
            int grow = m0 + row;
            if (grow >= sege) continue;
            if constexpr (GELU) {
                unsigned short* h = (unsigned short*)outp;
                size_t base = (size_t)grow * ND + n0;
#pragma unroll
                for (int n = 0; n < 4; ++n) {
                    int col = wc * 64 + n * 16 + lr;
                    float v = acc[m][n][r] + be[col];
                    float u = v * (0.7978845608f + 0.0356774081f * v * v);
                    float g = v / (1.0f + __expf(-2.0f * u));
                    h[base + col] = f2bf(g);
                }
            } else {
                float* out = (float*)outp;
                int tok = perm[grow];
                size_t base = (size_t)tok * ND + n0;
#pragma unroll
                for (int n = 0; n < 4; ++n) {
                    int col = wc * 64 + n * 16 + lr;
                    out[base + col] = acc[m][n][r] + be[col];
                }
            }
        }
    }
}

extern "C" void kernel_launch(void* const* d_in, const int* in_sizes, int n_in,
                              void* d_out, int out_size, void* d_ws, size_t ws_size,
                              hipStream_t stream) {
    const float* x   = (const float*)d_in[0];
    const int*   idx = (const int*)d_in[1];
    const float* w1  = (const float*)d_in[2];
    const float* w2  = (const float*)d_in[3];
    const float* b1  = (const float*)d_in[4];
    const float* b2  = (const float*)d_in[5];
    float* out = (float*)d_out;

    int* perm  = (int*)d_ws;
    int* off   = perm + TOKENS;
    int* table = off + 16;
    unsigned short* xg  = (unsigned short*)((char*)d_ws + 65536);
    unsigned short* h   = xg + (size_t)TOKENS * IN_F;             // 64 MB
    unsigned short* w1t = h + (size_t)TOKENS * HID_F;             // 64 MB
    unsigned short* w2t = w1t + (size_t)NEXP * IN_F * HID_F;      // 64 MB (fused only)
    const size_t need_fused = 65536
        + (size_t)TOKENS * IN_F * 2
        + (size_t)TOKENS * HID_F * 2
        + (size_t)NEXP * IN_F * HID_F * 2 * 2;
    const bool fused = (ws_size >= need_fused);

    hipLaunchKernelGGL(sort_kernel, dim3(1), dim3(1024), 0, stream, idx, perm, off, table);
    hipLaunchKernelGGL(fused_pre, dim3(TOKENS + NEXP * (IN_F / 64) * (HID_F / 64)),
                       dim3(256), 0, stream, x, perm, xg, w1, w1t);

    const int g1 = (HID_F / 256) * TSLOTS;                    // 640 GEMM1 tiles
    const int t2 = NEXP * (OUT_F / 64) * (HID_F / 64) / 2;    // 4096 W2t blocks
    if (fused) {
        hipLaunchKernelGGL((moe_gemm8p<IN_F, HID_F, true>), dim3(g1 + t2), dim3(512),
                           0, stream, xg, w1t, b1, perm, off, table, (void*)h, w2, w2t);
        hipLaunchKernelGGL((moe_gemm8p<HID_F, OUT_F, false>),
                           dim3((OUT_F / 256) * TSLOTS), dim3(512),
                           0, stream, h, w2t, b2, perm, off, table, (void*)out,
                           (const float*)nullptr, (unsigned short*)nullptr);
    } else {
        hipLaunchKernelGGL((moe_gemm8p<IN_F, HID_F, true>), dim3(g1), dim3(512),
                           0, stream, xg, w1t, b1, perm, off, table, (void*)h,
                           (const float*)nullptr, (unsigned short*)nullptr);
        hipLaunchKernelGGL(transp, dim3(OUT_F / 64, HID_F / 64, NEXP), dim3(256), 0, stream,
                           w2, w1t, HID_F, OUT_F);
        hipLaunchKernelGGL((moe_gemm8p<HID_F, OUT_F, false>),
                           dim3((OUT_F / 256) * TSLOTS), dim3(512),
                           0, stream, h, w1t, b2, perm, off, table, (void*)out,
                           (const float*)nullptr, (unsigned short*)nullptr);
    }
}

// Round 20
// 294.328 us; speedup vs baseline: 1.1400x; 1.0663x over previous
//
#include <hip/hip_runtime.h>
#include <hip/hip_bf16.h>
#include <math.h>

#define TOKENS 8192
#define IN_F   1024
#define HID_F  4096
#define OUT_F  1024
#define NEXP   8
#define TSLOTS 40   // max total 256-row M-tiles: TOKENS/256 + NEXP partials

typedef __attribute__((ext_vector_type(8))) short bf16x8;
typedef __attribute__((ext_vector_type(4))) float f32x4;
typedef __attribute__((ext_vector_type(8))) unsigned short u16x8;

__device__ __forceinline__ unsigned short f2bf(float f) {
    unsigned int u = __float_as_uint(f);
    u += 0x7fffu + ((u >> 16) & 1u);   // round-to-nearest-even
    return (unsigned short)(u >> 16);
}

__device__ __forceinline__ void gload_lds16(const unsigned short* g, unsigned char* lds) {
    __builtin_amdgcn_global_load_lds(
        (const __attribute__((address_space(1))) void*)g,
        (__attribute__((address_space(3))) void*)lds, 16, 0, 0);
}

// ---------------- sort body: 1024 threads (R13-verified form) ---------------
__device__ void sort_body(const int* __restrict__ idx, int* __restrict__ perm,
                          int* __restrict__ off, int* __restrict__ table) {
    __shared__ int cnt[NEXP];
    __shared__ int base[NEXP];
    const int tid = threadIdx.x, lane = tid & 63;
    if (tid < NEXP) cnt[tid] = 0;
    __syncthreads();
    for (int i = tid; i < TOKENS; i += 1024) {
        int e = idx[i];
#pragma unroll
        for (int ex = 0; ex < NEXP; ++ex) {
            unsigned long long m = __ballot(e == ex);
            if (lane == 0 && m) atomicAdd(&cnt[ex], __popcll(m));
        }
    }
    __syncthreads();
    if (tid == 0) {
        int s = 0;
        for (int e = 0; e < NEXP; ++e) { off[e] = s; base[e] = s; s += cnt[e]; }
        off[NEXP] = s;
        int t = 0;
        for (int e = 0; e < NEXP; ++e)
            for (int m0 = off[e]; m0 < off[e + 1]; m0 += 256)
                table[t++] = (e << 13) | m0;
        for (; t < TSLOTS; ++t) table[t] = -1;
    }
    __syncthreads();
    for (int i = tid; i < TOKENS; i += 1024) {
        int e = idx[i];
#pragma unroll
        for (int ex = 0; ex < NEXP; ++ex) {
            unsigned long long m = __ballot(e == ex);
            if (e == ex) {
                int lead = (int)__ffsll((long long)m) - 1;
                int pos = 0;
                if (lane == lead) pos = atomicAdd(&base[ex], __popcll(m));
                pos = __shfl(pos, lead);
                pos += __popcll(m & ((1ULL << lane) - 1ULL));
                perm[pos] = i;
            }
        }
    }
}

// ------- transpose tile body: fp32 [R][C] block (by,bx) -> bf16 [C][R] ------
__device__ __forceinline__ void transp_tile(const float* __restrict__ in,
                                            unsigned short* __restrict__ out,
                                            int R, int C, int e, int by, int bx,
                                            unsigned short* T, int st) {
    const int r0 = by * 64, c0 = bx * 64;
    const int rr = st >> 4, cc = st & 15;
    const float* ip = in + ((size_t)e * R + r0) * C + c0;
#pragma unroll
    for (int p = 0; p < 4; ++p) {
        int r = p * 16 + rr;
        float4 v = *(const float4*)(ip + (size_t)r * C + cc * 4);
        T[(cc * 4 + 0) * 65 + r] = f2bf(v.x);
        T[(cc * 4 + 1) * 65 + r] = f2bf(v.y);
        T[(cc * 4 + 2) * 65 + r] = f2bf(v.z);
        T[(cc * 4 + 3) * 65 + r] = f2bf(v.w);
    }
    __syncthreads();
    unsigned short* op = out + ((size_t)e * C + c0) * R + r0;
    const int c = st >> 2, ch = st & 3;
    u16x8 a, b;
#pragma unroll
    for (int i = 0; i < 8; ++i) a[i] = T[c * 65 + ch * 16 + i];
#pragma unroll
    for (int i = 0; i < 8; ++i) b[i] = T[c * 65 + ch * 16 + 8 + i];
    *(u16x8*)(op + (size_t)c * R + ch * 16) = a;
    *(u16x8*)(op + (size_t)c * R + ch * 16 + 8) = b;
}

// ---------------- standalone transpose (fallback path) ----------------------
__global__ void transp(const float* __restrict__ in, unsigned short* __restrict__ out,
                       int R, int C) {
    __shared__ unsigned short T[64 * 65];
    transp_tile(in, out, R, C, blockIdx.z, blockIdx.y, blockIdx.x, T, threadIdx.x);
}

// ------- k1 (1024 thr): block 0 = full-speed 1024-thread sort;
//         blocks 1..2048 = 4 concurrent W1-transpose sub-tiles each.
//         Sort (~13us) overlaps the BW-bound W1 transpose instead of
//         serializing the whole pre-pass (R15's failure was a 256-thr sort).
__global__ void pre_sort_w1t(const int* __restrict__ idx, int* __restrict__ perm,
                             int* __restrict__ off, int* __restrict__ table,
                             const float* __restrict__ w1,
                             unsigned short* __restrict__ w1t) {
    __shared__ unsigned short T[4 * 4224];
    const int bid = blockIdx.x;
    if (bid == 0) { sort_body(idx, perm, off, table); return; }
    const int sub = threadIdx.x >> 8, st = threadIdx.x & 255;
    const int id = (bid - 1) * 4 + sub;     // 8192 tiles: 8 x 16 x 64
    const int e = id >> 10, rem = id & 1023;
    const int by = rem >> 6, bx = rem & 63;
    transp_tile(w1, w1t, IN_F, HID_F, e, by, bx, T + sub * 4224, st);
}

// ---------------- k2: gather + convert x into sorted bf16 rows --------------
__global__ void gather_x(const float* __restrict__ x, const int* __restrict__ perm,
                         unsigned short* __restrict__ xg) {
    const int row = blockIdx.x, t = threadIdx.x;
    const int src = perm[row];
    float4 v = *(const float4*)(x + (size_t)src * IN_F + t * 4);
    unsigned long long pk =
        (unsigned long long)f2bf(v.x) |
        ((unsigned long long)f2bf(v.y) << 16) |
        ((unsigned long long)f2bf(v.z) << 32) |
        ((unsigned long long)f2bf(v.w) << 48);
    *(unsigned long long*)(xg + (size_t)row * IN_F + t * 4) = pk;
}

// -------- grouped GEMM: 256x256, BK=64, 8 waves, 8-phase counted-vmcnt ------
// R8/R13/R19-verified schedule + panel-paired logical order (A L2 reuse).
#define RD_A(RB, HALF) \
  _Pragma("unroll") for (int m_ = 0; m_ < 4; ++m_) { \
    const int row_ = wr * 128 + (HALF) * 64 + m_ * 16 + lr; \
    _Pragma("unroll") for (int kk_ = 0; kk_ < 2; ++kk_) \
      aR[m_][kk_] = *(const bf16x8*)((RB) + row_ * 128 + (((kk_ * 4 + hk) << 4) ^ xorc)); }

#define RD_B(RB, NH, DST) \
  _Pragma("unroll") for (int nn_ = 0; nn_ < 2; ++nn_) { \
    const int row_ = wc * 64 + ((NH) * 2 + nn_) * 16 + lr; \
    _Pragma("unroll") for (int kk_ = 0; kk_ < 2; ++kk_) \
      DST[nn_][kk_] = *(const bf16x8*)((RB) + 32768 + row_ * 128 + (((kk_ * 4 + hk) << 4) ^ xorc)); }

#define MFMA_Q(MH, NH, B) \
  __builtin_amdgcn_s_setprio(1); \
  _Pragma("unroll") for (int m_ = 0; m_ < 4; ++m_) \
    _Pragma("unroll") for (int nn_ = 0; nn_ < 2; ++nn_) \
      _Pragma("unroll") for (int kk_ = 0; kk_ < 2; ++kk_) \
        acc[(MH) * 4 + m_][(NH) * 2 + nn_] = __builtin_amdgcn_mfma_f32_16x16x32_bf16( \
            aR[m_][kk_], B[nn_][kk_], acc[(MH) * 4 + m_][(NH) * 2 + nn_], 0, 0, 0); \
  __builtin_amdgcn_s_setprio(0);

template<int K, int ND, bool GELU>
__launch_bounds__(512, 2)
__global__ void moe_gemm8p(const unsigned short* __restrict__ A,
                           const unsigned short* __restrict__ W,
                           const float* __restrict__ bias,
                           const int* __restrict__ perm,
                           const int* __restrict__ off,
                           const int* __restrict__ table,
                           void* __restrict__ outp,
                           const float* __restrict__ w2src,
                           unsigned short* __restrict__ w2t) {
    const int nwg = (ND / 256) * TSLOTS;

    __shared__ __align__(16) unsigned char L[131072];  // 2 buf x (A 32K + B 32K)
    const int tid = threadIdx.x;

    if ((int)blockIdx.x >= nwg) {
        // ---- fused W2 transpose: [E][4096][1024] -> [E][1024][4096] ----
        const int sub = tid >> 8, st = tid & 255;
        const int id2 = ((int)blockIdx.x - nwg) * 2 + sub;
        const int e = id2 >> 10, rem = id2 & 1023;
        const int by = rem >> 4, bx = rem & 15;
        unsigned short* T = (unsigned short*)(L + sub * 8448);
        transp_tile(w2src, w2t, HID_F, OUT_F, e, by, bx, T, st);
        return;
    }

    const int chunk = nwg >> 3;
    const int logical = ((int)blockIdx.x & 7) * chunk + ((int)blockIdx.x >> 3);
    // panel-paired decode: consecutive logicals = same slot, adjacent panels
    const int pr   = logical / (2 * TSLOTS);
    const int rem2 = logical - pr * (2 * TSLOTS);
    const int ts = rem2 >> 1;
    const int nt = pr * 2 + (rem2 & 1);
    const int te = table[ts];
    if (te < 0) return;
    const int e  = te >> 13;
    const int m0 = te & 8191;
    const int sege = off[e + 1];
    const int n0 = nt * 256;

    const int wid = tid >> 6, lane = tid & 63;
    const int wr = wid >> 2, wc = wid & 3;
    const int lr = lane & 15, hk = lane >> 4;

    const unsigned short* We = W + (size_t)e * ND * K + (size_t)n0 * K;

    const int srow8 = lane >> 3;
    const int sch   = (lane & 7) ^ srow8;   // pre-swizzled source chunk
    const unsigned short* aSrc[4];
    const unsigned short* wSrc[4];
#pragma unroll
    for (int cc = 0; cc < 4; ++cc) {
        int rt = cc * 64 + wid * 8 + srow8;
        int ga = m0 + rt; if (ga > TOKENS - 1) ga = TOKENS - 1;
        aSrc[cc] = A  + (size_t)ga * K + sch * 8;
        wSrc[cc] = We + (size_t)rt * K + sch * 8;
    }
    const int dstBase = wid * 1024;

    constexpr int NT = K / 64;

    auto stageH = [&](int tile, int h) {
        const int buf = (tile & 1) * 65536;
        const int op  = (h >> 1) * 32768;
        const int c0_ = (h & 1) * 2;
        const int ko  = tile * 64;
#pragma unroll
        for (int j = 0; j < 2; ++j) {
            int cc = c0_ + j;
            const unsigned short* s = (h < 2) ? (aSrc[cc] + ko) : (wSrc[cc] + ko);
            gload_lds16(s, L + buf + op + cc * 8192 + dstBase);
        }
    };

    f32x4 acc[8][4];
#pragma unroll
    for (int i = 0; i < 8; ++i)
#pragma unroll
        for (int j = 0; j < 4; ++j) acc[i][j] = (f32x4){0.f, 0.f, 0.f, 0.f};

    bf16x8 aR[4][2], b0R[2][2], b1R[2][2];
    const int xorc = (lr & 7) << 4;
    const unsigned char* rb0 = L;
    const unsigned char* rb1 = L + 65536;

    // prologue: tile0 all 4 halves + A0(tile1); wait own tile0, rendezvous.
    stageH(0, 0); stageH(0, 1); stageH(0, 2); stageH(0, 3);
    stageH(1, 0);
    asm volatile("s_waitcnt vmcnt(2)" ::: "memory");
    __builtin_amdgcn_s_barrier();
    __builtin_amdgcn_sched_barrier(0);

#pragma unroll 1
    for (int i = 0; i < NT / 2; ++i) {
        const int T1 = 2 * i + 1;
        const bool lastIt = (i == NT / 2 - 1);
        // ---- ph0: q00 of T0 ----
        RD_A(rb0, 0); RD_B(rb0, 0, b0R);
        stageH(T1, 1);                       // A1(T1)
        __builtin_amdgcn_s_barrier();
        MFMA_Q(0, 0, b0R);
        __builtin_amdgcn_s_barrier();
        // ---- ph1: q01 ----
        RD_B(rb0, 1, b1R);
        stageH(T1, 2);                       // B0(T1)
        __builtin_amdgcn_s_barrier();
        MFMA_Q(0, 1, b1R);
        __builtin_amdgcn_s_barrier();
        // ---- ph2: q11 ----
        RD_A(rb0, 1);
        stageH(T1, 3);                       // B1(T1)
        __builtin_amdgcn_s_barrier();
        MFMA_Q(1, 1, b1R);
        __builtin_amdgcn_s_barrier();
        // ---- ph3: q10 (b0R persists from ph0); publish T1 ----
        if (!lastIt) stageH(T1 + 1, 0);      // A0(T0+2)
        __builtin_amdgcn_s_barrier();
        MFMA_Q(1, 0, b0R);
        if (lastIt) { asm volatile("s_waitcnt vmcnt(0)" ::: "memory"); }
        else        { asm volatile("s_waitcnt vmcnt(2)" ::: "memory"); }
        __builtin_amdgcn_s_barrier();        // T1 visible to all waves
        __builtin_amdgcn_sched_barrier(0);
        // ---- ph4: q00 of T1 ----
        RD_A(rb1, 0); RD_B(rb1, 0, b0R);
        if (!lastIt) stageH(T1 + 1, 1);      // A1(T0+2)
        __builtin_amdgcn_s_barrier();
        MFMA_Q(0, 0, b0R);
        __builtin_amdgcn_s_barrier();
        // ---- ph5: q01 ----
        RD_B(rb1, 1, b1R);
        if (!lastIt) stageH(T1 + 1, 2);      // B0(T0+2)
        __builtin_amdgcn_s_barrier();
        MFMA_Q(0, 1, b1R);
        __builtin_amdgcn_s_barrier();
        // ---- ph6: q11 ----
        RD_A(rb1, 1);
        if (!lastIt) stageH(T1 + 1, 3);      // B1(T0+2)
        __builtin_amdgcn_s_barrier();
        MFMA_Q(1, 1, b1R);
        __builtin_amdgcn_s_barrier();
        // ---- ph7: q10 (b0R from ph4); publish T0+2 ----
        if (!lastIt) stageH(T1 + 2, 0);      // A0(T1+2)
        __builtin_amdgcn_s_barrier();
        MFMA_Q(1, 0, b0R);
        if (!lastIt) { asm volatile("s_waitcnt vmcnt(2)" ::: "memory"); }
        __builtin_amdgcn_s_barrier();        // T0+2 visible to all waves
        __builtin_amdgcn_sched_barrier(0);
    }

    // epilogue
    const float* be = bias + (size_t)e * ND + n0;
#pragma unroll
    for (int m = 0; m < 8; ++m) {
#pragma unroll
        for (int r = 0; r < 4; ++r) {
            int row = wr * 128 + m * 16 + hk * 4 + r;
            int grow = m0 + row;
            if (grow >= sege) continue;
            if constexpr (GELU) {
                unsigned short* h = (unsigned short*)outp;
                size_t base = (size_t)grow * ND + n0;
#pragma unroll
                for (int n = 0; n < 4; ++n) {
                    int col = wc * 64 + n * 16 + lr;
                    float v = acc[m][n][r] + be[col];
                    float u = v * (0.7978845608f + 0.0356774081f * v * v);
                    float g = v / (1.0f + __expf(-2.0f * u));
                    h[base + col] = f2bf(g);
                }
            } else {
                float* out = (float*)outp;
                int tok = perm[grow];
                size_t base = (size_t)tok * ND + n0;
#pragma unroll
                for (int n = 0; n < 4; ++n) {
                    int col = wc * 64 + n * 16 + lr;
                    out[base + col] = acc[m][n][r] + be[col];
                }
            }
        }
    }
}

extern "C" void kernel_launch(void* const* d_in, const int* in_sizes, int n_in,
                              void* d_out, int out_size, void* d_ws, size_t ws_size,
                              hipStream_t stream) {
    const float* x   = (const float*)d_in[0];
    const int*   idx = (const int*)d_in[1];
    const float* w1  = (const float*)d_in[2];
    const float* w2  = (const float*)d_in[3];
    const float* b1  = (const float*)d_in[4];
    const float* b2  = (const float*)d_in[5];
    float* out = (float*)d_out;

    int* perm  = (int*)d_ws;
    int* off   = perm + TOKENS;
    int* table = off + 16;
    unsigned short* xg  = (unsigned short*)((char*)d_ws + 65536);
    unsigned short* h   = xg + (size_t)TOKENS * IN_F;             // 64 MB
    unsigned short* w1t = h + (size_t)TOKENS * HID_F;             // 64 MB
    unsigned short* w2t = w1t + (size_t)NEXP * IN_F * HID_F;      // 64 MB (fused only)
    const size_t need_fused = 65536
        + (size_t)TOKENS * IN_F * 2
        + (size_t)TOKENS * HID_F * 2
        + (size_t)NEXP * IN_F * HID_F * 2 * 2;
    const bool fused = (ws_size >= need_fused);

    // k1: sort (block 0, full 1024-thr speed) overlapped with W1 transpose
    hipLaunchKernelGGL(pre_sort_w1t, dim3(1 + NEXP * (IN_F / 64) * (HID_F / 64) / 4),
                       dim3(1024), 0, stream, idx, perm, off, table, w1, w1t);
    // k2: gather (depends on perm)
    hipLaunchKernelGGL(gather_x, dim3(TOKENS), dim3(256), 0, stream, x, perm, xg);

    const int g1 = (HID_F / 256) * TSLOTS;                    // 640 GEMM1 tiles
    const int t2 = NEXP * (OUT_F / 64) * (HID_F / 64) / 2;    // 4096 W2t blocks
    if (fused) {
        hipLaunchKernelGGL((moe_gemm8p<IN_F, HID_F, true>), dim3(g1 + t2), dim3(512),
                           0, stream, xg, w1t, b1, perm, off, table, (void*)h, w2, w2t);
        hipLaunchKernelGGL((moe_gemm8p<HID_F, OUT_F, false>),
                           dim3((OUT_F / 256) * TSLOTS), dim3(512),
                           0, stream, h, w2t, b2, perm, off, table, (void*)out,
                           (const float*)nullptr, (unsigned short*)nullptr);
    } else {
        hipLaunchKernelGGL((moe_gemm8p<IN_F, HID_F, true>), dim3(g1), dim3(512),
                           0, stream, xg, w1t, b1, perm, off, table, (void*)h,
                           (const float*)nullptr, (unsigned short*)nullptr);
        hipLaunchKernelGGL(transp, dim3(OUT_F / 64, HID_F / 64, NEXP), dim3(256), 0, stream,
                           w2, w1t, HID_F, OUT_F);
        hipLaunchKernelGGL((moe_gemm8p<HID_F, OUT_F, false>),
                           dim3((OUT_F / 256) * TSLOTS), dim3(512),
                           0, stream, h, w1t, b2, perm, off, table, (void*)out,
                           (const float*)nullptr, (unsigned short*)nullptr);
    }
}